// Round 2
// baseline (292.460 us; speedup 1.0000x reference)
//
#include <hip/hip_runtime.h>

// WaveNet inference, exploiting: (1) only last timestep of head matters,
// (2) skip is overwritten each layer (only layer 15's skip used),
// (3) receptive field at t=T-1 is only 77 steps.
// All float tensors are float32 (round-1 NaN proved bf16 guess wrong).

#define BB 16
#define TT 8192
#define LL 16
#define W0 77   // receptive-field window of x0

__global__ __launch_bounds__(256) void wavenet_kernel(
    const int* __restrict__ tokens,
    const float* __restrict__ emb,
    const float* __restrict__ init_w, const float* __restrict__ init_b,
    const float* __restrict__ dil_w,  const float* __restrict__ dil_b,
    const float* __restrict__ filt_w, const float* __restrict__ filt_b,
    const float* __restrict__ gate_w, const float* __restrict__ gate_b,
    const float* __restrict__ res_w,  const float* __restrict__ res_b,
    const float* __restrict__ skip_w, const float* __restrict__ skip_b,
    const float* __restrict__ end1_w, const float* __restrict__ end1_b,
    const float* __restrict__ end2_w, const float* __restrict__ end2_b,
    const float* __restrict__ fc1_w,  const float* __restrict__ fc1_b,
    const float* __restrict__ fc2_w,  const float* __restrict__ fc2_b,
    const float* __restrict__ fc3_w,  const float* __restrict__ fc3_b,
    const float* __restrict__ fc4_w,  const float* __restrict__ fc4_b,
    float* __restrict__ out)
{
  __shared__ float xbuf[W0 * 32];        // [u][c], u=0 is t=T-1
  __shared__ float resbuf[(W0 - 1) * 32];
  __shared__ float xmid[(W0 - 2) * 32];
  __shared__ float wts[7 * 1024];        // transposed layer weights (also init_w^T: 3200)
  __shared__ float bias[4 * 32];
  __shared__ int   tok[W0];
  __shared__ float vecA[256], vecB[256];

  const int b = blockIdx.x;
  const int tid = threadIdx.x;

  // ---- stage 0: tokens + init_w^T into LDS ----
  if (tid < W0) tok[tid] = tokens[b * TT + (TT - 1 - tid)];
  for (int idx = tid; idx < 100 * 32; idx += 256) {
    int e = idx >> 5, c = idx & 31;
    wts[idx] = init_w[c * 100 + e];   // iwT[e][c]
  }
  if (tid < 32) bias[tid] = init_b[tid];
  __syncthreads();

  // x0[u][c] = init_b[c] + sum_e init_w[c][e] * emb[tok[u]][e]
  for (int idx = tid; idx < W0 * 32; idx += 256) {
    int u = idx >> 5, c = idx & 31;
    const float* er = emb + tok[u] * 100;
    float acc = bias[c];
    for (int e = 0; e < 100; e++) acc += wts[e * 32 + c] * er[e];
    xbuf[idx] = acc;
  }
  __syncthreads();

  // ---- 16 layers over shrinking window ----
  int Win = W0;
  for (int i = 0; i < LL; i++) {
    const int d = 1 << (i & 3);
    const int Wout = Win - d - 1;

    // stage weights transposed: [rc][c] layout, conflict-free reads
    for (int idx = tid; idx < 1024; idx += 256) {
      int rc = idx >> 5, c = idx & 31;
      int base = (i * 32 + c) * 32 + rc;
      wts[idx]        = dil_w[base * 2 + 0];
      wts[1024 + idx] = dil_w[base * 2 + 1];
      wts[2048 + idx] = filt_w[base * 2 + 0];
      wts[3072 + idx] = filt_w[base * 2 + 1];
      wts[4096 + idx] = gate_w[base * 2 + 0];
      wts[5120 + idx] = gate_w[base * 2 + 1];
      wts[6144 + idx] = res_w[base];
    }
    if (tid < 32) {
      bias[tid]      = dil_b[i * 32 + tid];
      bias[32 + tid] = filt_b[i * 32 + tid];
      bias[64 + tid] = gate_b[i * 32 + tid];
      bias[96 + tid] = res_b[i * 32 + tid];
    }
    __syncthreads();

    // residual[vr][c] = db[c] + D0@x[vr+d] + D1@x[vr], vr in [0, Wout]
    // (vr = T - j; taps are x at j-d-1 and j-1)
    for (int idx = tid; idx < (Wout + 1) * 32; idx += 256) {
      int vr = idx >> 5, c = idx & 31;
      float acc = bias[c];
      const float* xa = xbuf + (vr + d) * 32;
      const float* xz = xbuf + vr * 32;
      for (int rc = 0; rc < 32; rc++)
        acc += wts[rc * 32 + c] * xa[rc] + wts[1024 + rc * 32 + c] * xz[rc];
      resbuf[idx] = acc;
    }
    __syncthreads();

    // f/g at uf = T-1-t in [0, Wout-1]: F0@res[t](vr=uf+1) + F1@res[t+1](vr=uf)
    for (int idx = tid; idx < Wout * 32; idx += 256) {
      int uf = idx >> 5, c = idx & 31;
      float af = bias[32 + c], ag = bias[64 + c];
      const float* r1 = resbuf + (uf + 1) * 32;  // residual[t]
      const float* r0 = resbuf + uf * 32;        // residual[t+1]
      for (int rc = 0; rc < 32; rc++) {
        float a = r1[rc], z = r0[rc];
        af += wts[2048 + rc * 32 + c] * a + wts[3072 + rc * 32 + c] * z;
        ag += wts[4096 + rc * 32 + c] * a + wts[5120 + rc * 32 + c] * z;
      }
      float fv = tanhf(af);
      float gv = 1.f / (1.f + expf(-ag));
      xmid[idx] = fv * gv;
    }
    __syncthreads();

    // xnext[uf][c] = rb[c] + R@xmid[uf] + residual[t] (vr=uf+1)
    for (int idx = tid; idx < Wout * 32; idx += 256) {
      int uf = idx >> 5, c = idx & 31;
      float acc = bias[96 + c] + resbuf[(uf + 1) * 32 + c];
      const float* xm = xmid + uf * 32;
      for (int rc = 0; rc < 32; rc++)
        acc += wts[6144 + rc * 32 + c] * xm[rc];
      xbuf[idx] = acc;
    }
    __syncthreads();
    Win = Wout;
  }

  // ---- tail: only layer 15's skip at t=T-1 matters; xmid[0..31] holds it ----
  // s = relu(skip_w[15] @ xmid + skip_b[15])
  {
    float acc = skip_b[15 * 256 + tid];
    const float* wr = skip_w + (15 * 256 + tid) * 32;
    for (int c = 0; c < 32; c++) acc += wr[c] * xmid[c];
    vecA[tid] = fmaxf(acc, 0.f);
  }
  __syncthreads();
  // h1 = relu(end1 @ s + b)
  {
    float acc = end1_b[tid];
    const float* wr = end1_w + tid * 256;
    for (int k = 0; k < 256; k++) acc += wr[k] * vecA[k];
    vecB[tid] = fmaxf(acc, 0.f);
  }
  __syncthreads();
  // h2 = end2 @ h1 + b  (no relu)
  {
    float acc = end2_b[tid];
    const float* wr = end2_w + tid * 256;
    for (int k = 0; k < 256; k++) acc += wr[k] * vecB[k];
    vecA[tid] = acc;
  }
  __syncthreads();
  // fc1 (128 out of 256 in) + relu
  if (tid < 128) {
    float acc = fc1_b[tid];
    const float* wr = fc1_w + tid * 256;
    for (int k = 0; k < 256; k++) acc += wr[k] * vecA[k];
    vecB[tid] = fmaxf(acc, 0.f);
  }
  __syncthreads();
  // fc2 (128x128) + relu
  if (tid < 128) {
    float acc = fc2_b[tid];
    const float* wr = fc2_w + tid * 128;
    for (int k = 0; k < 128; k++) acc += wr[k] * vecB[k];
    vecA[tid] = fmaxf(acc, 0.f);
  }
  __syncthreads();
  // fc3 (64x128) + relu
  if (tid < 64) {
    float acc = fc3_b[tid];
    const float* wr = fc3_w + tid * 128;
    for (int k = 0; k < 128; k++) acc += wr[k] * vecA[k];
    vecB[tid] = fmaxf(acc, 0.f);
  }
  __syncthreads();
  // fc4 (256x64), final
  {
    float acc = fc4_b[tid];
    const float* wr = fc4_w + tid * 64;
    for (int k = 0; k < 64; k++) acc += wr[k] * vecB[k];
    out[b * 256 + tid] = acc;
  }
}

extern "C" void kernel_launch(void* const* d_in, const int* in_sizes, int n_in,
                              void* d_out, int out_size, void* d_ws, size_t ws_size,
                              hipStream_t stream) {
  wavenet_kernel<<<BB, 256, 0, stream>>>(
      (const int*)d_in[0],    (const float*)d_in[1],  (const float*)d_in[2],  (const float*)d_in[3],
      (const float*)d_in[4],  (const float*)d_in[5],  (const float*)d_in[6],  (const float*)d_in[7],
      (const float*)d_in[8],  (const float*)d_in[9],  (const float*)d_in[10], (const float*)d_in[11],
      (const float*)d_in[12], (const float*)d_in[13], (const float*)d_in[14], (const float*)d_in[15],
      (const float*)d_in[16], (const float*)d_in[17], (const float*)d_in[18], (const float*)d_in[19],
      (const float*)d_in[20], (const float*)d_in[21], (const float*)d_in[22], (const float*)d_in[23],
      (const float*)d_in[24], (const float*)d_in[25], (float*)d_out);
}